// Round 3
// baseline (203.290 us; speedup 1.0000x reference)
//
#include <hip/hip_runtime.h>
#include <hip/hip_bf16.h>
#include <stdint.h>

// Shape fixed by reference: B=2, S=1024 -> M=2048; N=4096; K=4096
#define M_DIM 2048
#define N_DIM 4096
#define K_DIM 4096

#define BM 128
#define BN 128
#define BK 64   // 64 K-iters; 2x32 KiB LDS double-buffer; 16 MFMA/wave/iter

#define ATILE (BM * BK)   // ushorts per A buffer
#define BTILE (BN * BK)

typedef __attribute__((ext_vector_type(8))) short  short8;
typedef __attribute__((ext_vector_type(8))) __bf16 bf16x8;
typedef __attribute__((ext_vector_type(4))) float  f32x4;

// RNE float -> bf16 bits
__device__ __forceinline__ ushort f2bf(float f) {
    uint32_t u = __float_as_uint(f);
    u += 0x7fffu + ((u >> 16) & 1u);
    return (ushort)(u >> 16);
}

__device__ __forceinline__ void load_lds16(const void* g, void* l) {
    __builtin_amdgcn_global_load_lds(
        (const __attribute__((address_space(1))) void*)g,
        (__attribute__((address_space(3))) void*)l,
        16, 0, 0);
}

// ---------- fused conversion: x(fp32->bf16) and w(int->bf16) in one dispatch ----------
union Pack8 { ushort u[8]; uint4 v; };

#define XBLK ((M_DIM * (size_t)K_DIM) / 8 / 256)   // 4096 blocks, 8 elem/thread
#define WBLK (((size_t)N_DIM * K_DIM) / 16 / 256)  // 4096 blocks, 16 elem/thread

__global__ __launch_bounds__(256) void cvt_fused(const float* __restrict__ x,
                                                 const int* __restrict__ w,
                                                 ushort* __restrict__ Ab,
                                                 ushort* __restrict__ Bb) {
    const int b = blockIdx.x;
    if (b < (int)XBLK) {
        size_t i = ((size_t)b * 256 + threadIdx.x) * 8;
        float4 a = *(const float4*)(x + i);
        float4 c = *(const float4*)(x + i + 4);
        Pack8 t;
        t.u[0] = f2bf(a.x); t.u[1] = f2bf(a.y); t.u[2] = f2bf(a.z); t.u[3] = f2bf(a.w);
        t.u[4] = f2bf(c.x); t.u[5] = f2bf(c.y); t.u[6] = f2bf(c.z); t.u[7] = f2bf(c.w);
        *(uint4*)(Ab + i) = t.v;
    } else {
        size_t i = ((size_t)(b - (int)XBLK) * 256 + threadIdx.x) * 16;
        int4 a0 = *(const int4*)(w + i);
        int4 a1 = *(const int4*)(w + i + 4);
        int4 a2 = *(const int4*)(w + i + 8);
        int4 a3 = *(const int4*)(w + i + 12);
        Pack8 t0, t1;
        t0.u[0] = f2bf((float)a0.x); t0.u[1] = f2bf((float)a0.y);
        t0.u[2] = f2bf((float)a0.z); t0.u[3] = f2bf((float)a0.w);
        t0.u[4] = f2bf((float)a1.x); t0.u[5] = f2bf((float)a1.y);
        t0.u[6] = f2bf((float)a1.z); t0.u[7] = f2bf((float)a1.w);
        t1.u[0] = f2bf((float)a2.x); t1.u[1] = f2bf((float)a2.y);
        t1.u[2] = f2bf((float)a2.z); t1.u[3] = f2bf((float)a2.w);
        t1.u[4] = f2bf((float)a3.x); t1.u[5] = f2bf((float)a3.y);
        t1.u[6] = f2bf((float)a3.z); t1.u[7] = f2bf((float)a3.w);
        *(uint4*)(Bb + i)     = t0.v;
        *(uint4*)(Bb + i + 8) = t1.v;
    }
}

// ---------- GEMM: C = A(bf16)[M,K] x B(bf16)[N,K]^T, epilogue *scales[n]+bias[n] ----------
// 512 threads = 8 waves in 2x4; each wave owns 64x32 (acc[4][2] of 16x16x32).
// Double-buffered LDS (2 x 32 KiB): glds prefetch for tile k+1 issued BEFORE
// compute of tile k; single __syncthreads per iteration drains the prefetch
// (which has had a full compute phase to land) and guards buffer reuse.
// XOR-swizzled LDS columns (cg_phys = cg_log ^ (row&7)) applied on the GLOBAL
// source address, since glds LDS destinations are fixed at base+lane*16.

__global__ __launch_bounds__(512, 4) void gemm_bt_bf16(
    const ushort* __restrict__ A,      // [M,K] bf16 bits
    const ushort* __restrict__ B,      // [N,K] bf16 bits
    const float*  __restrict__ scales, // [N]
    const float*  __restrict__ bias,   // [N]
    float* __restrict__ C)             // [M,N]
{
    __shared__ __align__(16) ushort As[2 * ATILE];  // 32 KiB
    __shared__ __align__(16) ushort Bs[2 * BTILE];  // 32 KiB

    const int tid  = threadIdx.x;
    const int bm   = blockIdx.y;
    const int bn   = blockIdx.x;
    const int lane = tid & 63;
    const int wave = tid >> 6;           // 0..7
    const int wm   = (wave >> 2) * 64;   // 0 or 64
    const int wn   = (wave & 3) * 32;    // 0,32,64,96
    const int l16  = lane & 15;
    const int quad = lane >> 4;
    const int swz  = l16 & 7;

    // Staging: 512 thr x 16 B = 8 KiB/instr; 2 instrs per 16 KiB tile.
    // thread t -> LDS slot (row = t>>3 (+64), cg_phys = t&7); global col group
    // cg_log = cg_phys ^ (row&7). LDS byte addr linear in tid (glds layout rule).
    const int srow = tid >> 3;           // 0..63
    const int cgp  = tid & 7;
    const int cgl  = cgp ^ (srow & 7);   // (srow+64)&7 == srow&7

    const ushort* ga0 = A + (size_t)(bm * BM + srow)      * K_DIM + cgl * 8;
    const ushort* ga1 = A + (size_t)(bm * BM + 64 + srow) * K_DIM + cgl * 8;
    const ushort* gb0 = B + (size_t)(bn * BN + srow)      * K_DIM + cgl * 8;
    const ushort* gb1 = B + (size_t)(bn * BN + 64 + srow) * K_DIM + cgl * 8;
    const int la0 = srow * BK + cgp * 8;
    const int la1 = (64 + srow) * BK + cgp * 8;

    // Prologue: stage tile 0 into buffer 0.
    load_lds16(ga0, As + la0);
    load_lds16(ga1, As + la1);
    load_lds16(gb0, Bs + la0);
    load_lds16(gb1, Bs + la1);

    f32x4 acc[4][2] = {};

    int cur = 0;
    for (int k0 = 0; k0 < K_DIM; k0 += BK, cur ^= 1) {
        __syncthreads();   // drains glds for buf[cur]; all waves done reading buf[cur^1]

        const int kn = k0 + BK;
        if (kn < K_DIM) {  // prefetch next tile into the other buffer (in flight during compute)
            const int nb = (cur ^ 1);
            load_lds16(ga0 + kn, As + nb * ATILE + la0);
            load_lds16(ga1 + kn, As + nb * ATILE + la1);
            load_lds16(gb0 + kn, Bs + nb * BTILE + la0);
            load_lds16(gb1 + kn, Bs + nb * BTILE + la1);
        }

        const ushort* Ab = As + cur * ATILE;
        const ushort* Bb = Bs + cur * BTILE;

#pragma unroll
        for (int h = 0; h < 2; h++) {
            const int cp = (h * 4 + quad) ^ swz;   // physical col group to read
            short8 af[4], bfr[2];
#pragma unroll
            for (int i = 0; i < 4; i++)
                af[i] = *(const short8*)(Ab + (wm + i * 16 + l16) * BK + cp * 8);
#pragma unroll
            for (int j = 0; j < 2; j++)
                bfr[j] = *(const short8*)(Bb + (wn + j * 16 + l16) * BK + cp * 8);
#pragma unroll
            for (int i = 0; i < 4; i++)
#pragma unroll
                for (int j = 0; j < 2; j++)
                    acc[i][j] = __builtin_amdgcn_mfma_f32_16x16x32_bf16(
                        __builtin_bit_cast(bf16x8, af[i]),
                        __builtin_bit_cast(bf16x8, bfr[j]),
                        acc[i][j], 0, 0, 0);
        }
    }

    // Epilogue. C/D layout (verified m89): col = lane&15, row = quad*4 + reg.
#pragma unroll
    for (int j = 0; j < 2; j++) {
        const int col = bn * BN + wn + j * 16 + l16;
        const float s = scales[col];
        const float b = bias[col];
#pragma unroll
        for (int i = 0; i < 4; i++) {
            const int row0 = bm * BM + wm + i * 16 + quad * 4;
#pragma unroll
            for (int r = 0; r < 4; r++) {
                C[(size_t)(row0 + r) * N_DIM + col] = acc[i][j][r] * s + b;
            }
        }
    }
}

// ---------- launch ----------

extern "C" void kernel_launch(void* const* d_in, const int* in_sizes, int n_in,
                              void* d_out, int out_size, void* d_ws, size_t ws_size,
                              hipStream_t stream) {
    const float* x      = (const float*)d_in[0];   // [2,1024,4096] fp32
    const int*   w      = (const int*)d_in[1];     // [4096,4096] int, values in [-128,127]
    const float* scales = (const float*)d_in[2];   // [4096]
    const float* bias   = (const float*)d_in[3];   // [4096]
    float*       out    = (float*)d_out;           // [2,1024,4096] fp32

    ushort* Abf = (ushort*)d_ws;                                      // 16 MiB
    ushort* Bbf = (ushort*)((char*)d_ws + (size_t)M_DIM * K_DIM * 2); // 32 MiB

    cvt_fused<<<(int)(XBLK + WBLK), 256, 0, stream>>>(x, w, Abf, Bbf);

    dim3 grid(N_DIM / BN, M_DIM / BM);  // (32, 16) = 512 blocks
    gemm_bt_bf16<<<grid, 512, 0, stream>>>(Abf, Bbf, scales, bias, out);
}

// Round 4
// 164.051 us; speedup vs baseline: 1.2392x; 1.2392x over previous
//
#include <hip/hip_runtime.h>
#include <hip/hip_bf16.h>
#include <stdint.h>

// Shape fixed by reference: B=2, S=1024 -> M=2048; N=4096; K=4096
#define M_DIM 2048
#define N_DIM 4096
#define K_DIM 4096

#define BM 128
#define BN 128
#define BK 128            // int8 elements per K-tile = 128 B per row (same bytes as r3)

#define ATILE (BM * BK)   // bytes per A buffer (16 KiB)
#define BTILE (BN * BK)

typedef __attribute__((ext_vector_type(4))) int   int4v;
typedef __attribute__((ext_vector_type(4))) float f32x4;

__device__ __forceinline__ void load_lds16(const void* g, void* l) {
    __builtin_amdgcn_global_load_lds(
        (const __attribute__((address_space(1))) void*)g,
        (__attribute__((address_space(3))) void*)l,
        16, 0, 0);
}

// ---------- x: fp32 [M,K] -> int8 per-row dynamic quant; sx[row] = rowmax/127 ----------
__global__ __launch_bounds__(256) void quant_x(const float* __restrict__ x,
                                               int8_t* __restrict__ Aq,
                                               float* __restrict__ sx) {
    const int row = blockIdx.x;
    const int tid = threadIdx.x;
    const float4* xr = (const float4*)(x + (size_t)row * K_DIM);

    float4 v[4];
    float mx = 0.f;
#pragma unroll
    for (int p = 0; p < 4; p++) {
        v[p] = xr[p * 256 + tid];
        mx = fmaxf(mx, fmaxf(fmaxf(fabsf(v[p].x), fabsf(v[p].y)),
                             fmaxf(fabsf(v[p].z), fabsf(v[p].w))));
    }
#pragma unroll
    for (int off = 32; off >= 1; off >>= 1)
        mx = fmaxf(mx, __shfl_xor(mx, off, 64));

    __shared__ float wmax[4];
    __shared__ float smax;
    if ((tid & 63) == 0) wmax[tid >> 6] = mx;
    __syncthreads();
    if (tid == 0) {
        float m = fmaxf(fmaxf(wmax[0], wmax[1]), fmaxf(wmax[2], wmax[3]));
        m = fmaxf(m, 1e-20f);
        smax = m;
        sx[row] = m * (1.0f / 127.0f);
    }
    __syncthreads();
    const float inv = 127.0f / smax;

    int* out = (int*)Aq + (size_t)row * (K_DIM / 4);
#pragma unroll
    for (int p = 0; p < 4; p++) {
        int q0 = (int)__builtin_rintf(v[p].x * inv);
        int q1 = (int)__builtin_rintf(v[p].y * inv);
        int q2 = (int)__builtin_rintf(v[p].z * inv);
        int q3 = (int)__builtin_rintf(v[p].w * inv);
        q0 = max(-127, min(127, q0)); q1 = max(-127, min(127, q1));
        q2 = max(-127, min(127, q2)); q3 = max(-127, min(127, q3));
        out[p * 256 + tid] = (q0 & 255) | ((q1 & 255) << 8) |
                             ((q2 & 255) << 16) | ((q3 & 255) << 24);
    }
}

// ---------- w: int32 [N,K] (values in [-128,127]) -> int8, exact narrowing ----------
__global__ __launch_bounds__(256) void cvt_w8(const int* __restrict__ w,
                                              int8_t* __restrict__ Bq) {
    size_t i = ((size_t)blockIdx.x * 256 + threadIdx.x) * 16;
    int4 a0 = *(const int4*)(w + i);
    int4 a1 = *(const int4*)(w + i + 4);
    int4 a2 = *(const int4*)(w + i + 8);
    int4 a3 = *(const int4*)(w + i + 12);
    uint4 t;
    t.x = (a0.x & 255) | ((a0.y & 255) << 8) | ((a0.z & 255) << 16) | ((a0.w & 255) << 24);
    t.y = (a1.x & 255) | ((a1.y & 255) << 8) | ((a1.z & 255) << 16) | ((a1.w & 255) << 24);
    t.z = (a2.x & 255) | ((a2.y & 255) << 8) | ((a2.z & 255) << 16) | ((a2.w & 255) << 24);
    t.w = (a3.x & 255) | ((a3.y & 255) << 8) | ((a3.z & 255) << 16) | ((a3.w & 255) << 24);
    *(uint4*)(Bq + i) = t;
}

// ---------- GEMM: C = Aq[M,K] x Bq[N,K]^T (i8 MFMA, i32 acc), epilogue dequant ----------
// Tile bytes identical to round-3 bf16 kernel (128 rows x 128 B), but BK=128 int8
// elements -> 2x MACs per staged byte and 2x MFMA rate (mfma_i32_16x16x64_i8).
// A/B fragments use the same per-lane byte pattern, so any lane->k permutation
// inside the i8 MFMA cancels between A and B (dot over K is permutation-invariant).
// 512 thr = 8 waves 2x4; wave owns 64x32; dbuf LDS; XOR swizzle on global source.

__global__ __launch_bounds__(512, 4) void gemm_bt_i8(
    const int8_t* __restrict__ A,      // [M,K] int8
    const int8_t* __restrict__ B,      // [N,K] int8
    const float*  __restrict__ sx,     // [M] row dequant scale
    const float*  __restrict__ scales, // [N]
    const float*  __restrict__ bias,   // [N]
    float* __restrict__ C)             // [M,N]
{
    __shared__ __align__(16) int8_t As[2 * ATILE];  // 32 KiB
    __shared__ __align__(16) int8_t Bs[2 * BTILE];  // 32 KiB

    const int tid  = threadIdx.x;
    const int bm   = blockIdx.y;
    const int bn   = blockIdx.x;
    const int lane = tid & 63;
    const int wave = tid >> 6;           // 0..7
    const int wm   = (wave >> 2) * 64;   // 0 or 64
    const int wn   = (wave & 3) * 32;    // 0,32,64,96
    const int l16  = lane & 15;
    const int quad = lane >> 4;
    const int swz  = l16 & 7;

    // Staging: 512 thr x 16 B = 8 KiB/instr; 2 instrs per 16 KiB tile.
    // thread t -> LDS (row = t>>3 (+64), phys colgroup = t&7); global colgroup
    // = phys ^ (row&7). LDS byte addr = 16*t: linear in tid (glds layout rule).
    const int srow = tid >> 3;           // 0..63
    const int cgp  = tid & 7;
    const int cgl  = cgp ^ (srow & 7);

    const int8_t* ga0 = A + (size_t)(bm * BM + srow)      * K_DIM + cgl * 16;
    const int8_t* ga1 = A + (size_t)(bm * BM + 64 + srow) * K_DIM + cgl * 16;
    const int8_t* gb0 = B + (size_t)(bn * BN + srow)      * K_DIM + cgl * 16;
    const int8_t* gb1 = B + (size_t)(bn * BN + 64 + srow) * K_DIM + cgl * 16;
    const int la0 = srow * BK + cgp * 16;
    const int la1 = (64 + srow) * BK + cgp * 16;

    // Prologue: stage tile 0 into buffer 0.
    load_lds16(ga0, As + la0);
    load_lds16(ga1, As + la1);
    load_lds16(gb0, Bs + la0);
    load_lds16(gb1, Bs + la1);

    int4v acc[4][2] = {};

    int cur = 0;
    for (int k0 = 0; k0 < K_DIM; k0 += BK, cur ^= 1) {
        __syncthreads();   // drains glds for buf[cur]; all waves done with buf[cur^1]

        const int kn = k0 + BK;
        if (kn < K_DIM) {  // prefetch next tile, in flight during compute
            const int nb = (cur ^ 1);
            load_lds16(ga0 + kn, As + nb * ATILE + la0);
            load_lds16(ga1 + kn, As + nb * ATILE + la1);
            load_lds16(gb0 + kn, Bs + nb * BTILE + la0);
            load_lds16(gb1 + kn, Bs + nb * BTILE + la1);
        }

        const int8_t* Ab = As + cur * ATILE;
        const int8_t* Bb = Bs + cur * BTILE;

#pragma unroll
        for (int h = 0; h < 2; h++) {
            const int cp = (h * 4 + quad) ^ swz;   // physical colgroup to read
            int4v af[4], bfr[2];
#pragma unroll
            for (int i = 0; i < 4; i++)
                af[i] = *(const int4v*)(Ab + (wm + i * 16 + l16) * BK + cp * 16);
#pragma unroll
            for (int j = 0; j < 2; j++)
                bfr[j] = *(const int4v*)(Bb + (wn + j * 16 + l16) * BK + cp * 16);
#pragma unroll
            for (int i = 0; i < 4; i++)
#pragma unroll
                for (int j = 0; j < 2; j++)
                    acc[i][j] = __builtin_amdgcn_mfma_i32_16x16x64_i8(
                        af[i], bfr[j], acc[i][j], 0, 0, 0);
        }
    }

    // Row dequant scales for this lane's 16 output rows.
    float sxr[16];
#pragma unroll
    for (int i = 0; i < 4; i++)
#pragma unroll
        for (int r = 0; r < 4; r++)
            sxr[i * 4 + r] = sx[bm * BM + wm + i * 16 + quad * 4 + r];

    // Epilogue. C/D layout (shape-determined, verified): col = lane&15, row = quad*4 + reg.
#pragma unroll
    for (int j = 0; j < 2; j++) {
        const int col = bn * BN + wn + j * 16 + l16;
        const float s = scales[col];
        const float b = bias[col];
#pragma unroll
        for (int i = 0; i < 4; i++) {
            const int row0 = bm * BM + wm + i * 16 + quad * 4;
#pragma unroll
            for (int r = 0; r < 4; r++) {
                C[(size_t)(row0 + r) * N_DIM + col] =
                    (float)acc[i][j][r] * (sxr[i * 4 + r] * s) + b;
            }
        }
    }
}

// ---------- launch ----------

extern "C" void kernel_launch(void* const* d_in, const int* in_sizes, int n_in,
                              void* d_out, int out_size, void* d_ws, size_t ws_size,
                              hipStream_t stream) {
    const float* x      = (const float*)d_in[0];   // [2,1024,4096] fp32
    const int*   w      = (const int*)d_in[1];     // [4096,4096] int, values in [-128,127]
    const float* scales = (const float*)d_in[2];   // [4096]
    const float* bias   = (const float*)d_in[3];   // [4096]
    float*       out    = (float*)d_out;           // [2,1024,4096] fp32

    int8_t* Aq = (int8_t*)d_ws;                                        // 8 MiB
    int8_t* Bq = (int8_t*)d_ws + (size_t)M_DIM * K_DIM;                // 16 MiB
    float*  sx = (float*)((int8_t*)d_ws + (size_t)(M_DIM + N_DIM) * K_DIM); // 8 KiB

    quant_x<<<M_DIM, 256, 0, stream>>>(x, Aq, sx);
    cvt_w8<<<(int)((size_t)N_DIM * K_DIM / 16 / 256), 256, 0, stream>>>(w, Bq);

    dim3 grid(N_DIM / BN, M_DIM / BM);  // (32, 16) = 512 blocks
    gemm_bt_i8<<<grid, 512, 0, stream>>>(Aq, Bq, sx, scales, bias, out);
}